// Round 4
// baseline (352.330 us; speedup 1.0000x reference)
//
#include <hip/hip_runtime.h>

#define RM_EPS 1e-10f

// DPP cross-lane helper: returns, per lane, the source-lane value per CTRL;
// lanes with invalid sources yield `old_v` (BC=false) or 0 (BC=true).
// CDNA DPP convention: row_shr:n (0x110+n) pulls from lane i-n (shuffle-UP),
// row_shl:n (0x100+n) pulls from lane i+n, row_ror:n (0x120+n) rotates.
template<int CTRL, bool BC>
__device__ __forceinline__ float dpp_f(float old_v, float v) {
    return __int_as_float(__builtin_amdgcn_update_dpp(
        __float_as_int(old_v), __float_as_int(v), CTRL, 0xF, 0xF, BC));
}

// 16 lanes per ray (one DPP row), 8 consecutive samples per lane, 4 rays/wave.
// All cross-lane traffic is DPP (VALU) — zero DS instructions.
__global__ __launch_bounds__(256) void raymarch_kernel(
    const float* __restrict__ dens,   // (n_rays, 128)
    const float* __restrict__ feat,   // (n_rays, 128, 3)
    const float* __restrict__ len,    // (n_rays, 128)
    float* __restrict__ out,          // (n_rays, 4)
    int n_rays)
{
    const int lane  = (int)(threadIdx.x & 63);
    const int gwave = (int)((blockIdx.x * blockDim.x + threadIdx.x) >> 6);
    const int rseg  = lane >> 4;      // which of the wave's 4 rays (DPP row)
    const int sl    = lane & 15;      // sub-lane within the row
    const long long ray = (long long)gwave * 4 + rseg;
    if (ray >= n_rays) return;        // n_rays % 4 == 0 -> whole waves only

    // Per-lane contiguous vector loads (32 B dens, 32 B len, 96 B feat)
    const float4* dp = (const float4*)(dens + ray * 128 + sl * 8);
    const float4* lp = (const float4*)(len  + ray * 128 + sl * 8);
    const float4* fp = (const float4*)(feat + ray * 384 + sl * 24);
    const float4 d0 = dp[0], d1 = dp[1];
    const float4 l0 = lp[0], l1 = lp[1];
    const float4 f0 = fp[0], f1 = fp[1], f2 = fp[2];
    const float4 f3 = fp[3], f4 = fp[4], f5 = fp[5];

    const float d[8]  = {d0.x,d0.y,d0.z,d0.w, d1.x,d1.y,d1.z,d1.w};
    const float ll[8] = {l0.x,l0.y,l0.z,l0.w, l1.x,l1.y,l1.z,l1.w};
    const float f[24] = {f0.x,f0.y,f0.z,f0.w, f1.x,f1.y,f1.z,f1.w,
                         f2.x,f2.y,f2.z,f2.w, f3.x,f3.y,f3.z,f3.w,
                         f4.x,f4.y,f4.z,f4.w, f5.x,f5.y,f5.z,f5.w};

    // Serial local product of absorption terms over this lane's 8 samples
    float cp = 1.0f;
    #pragma unroll
    for (int i = 0; i < 8; ++i) cp *= (1.0f + RM_EPS - d[i]);

    // Inclusive multiplicative scan across the 16-lane row
    // (row_shr:n = shuffle-up; invalid low lanes get identity 1.0)
    float p = cp;
    p *= dpp_f<0x111, false>(1.0f, p);  // row_shr:1
    p *= dpp_f<0x112, false>(1.0f, p);  // row_shr:2
    p *= dpp_f<0x114, false>(1.0f, p);  // row_shr:4
    p *= dpp_f<0x118, false>(1.0f, p);  // row_shr:8
    // Exclusive prefix product (absorption before this lane's first sample)
    const float e = dpp_f<0x111, false>(1.0f, p);  // row_shr:1, lane0 -> 1.0

    // Serial weighted accumulation with running prefix
    float s0 = 0.f, s1 = 0.f, s2 = 0.f, sd = 0.f, sa = 0.f;
    float run = e;
    #pragma unroll
    for (int i = 0; i < 8; ++i) {
        const float wi = d[i] * run;
        s0 += wi * f[3*i+0];
        s1 += wi * f[3*i+1];
        s2 += wi * f[3*i+2];
        sd += wi * ll[i];
        sa += wi;
        run *= (1.0f + RM_EPS - d[i]);
    }

    // Rotate-and-add reduction: after ror 8,4,2,1 every lane holds the row sum
    s0 += dpp_f<0x128, true>(0.f, s0);
    s1 += dpp_f<0x128, true>(0.f, s1);
    s2 += dpp_f<0x128, true>(0.f, s2);
    sd += dpp_f<0x128, true>(0.f, sd);
    sa += dpp_f<0x128, true>(0.f, sa);
    s0 += dpp_f<0x124, true>(0.f, s0);
    s1 += dpp_f<0x124, true>(0.f, s1);
    s2 += dpp_f<0x124, true>(0.f, s2);
    sd += dpp_f<0x124, true>(0.f, sd);
    sa += dpp_f<0x124, true>(0.f, sa);
    s0 += dpp_f<0x122, true>(0.f, s0);
    s1 += dpp_f<0x122, true>(0.f, s1);
    s2 += dpp_f<0x122, true>(0.f, s2);
    sd += dpp_f<0x122, true>(0.f, sd);
    sa += dpp_f<0x122, true>(0.f, sa);
    s0 += dpp_f<0x121, true>(0.f, s0);
    s1 += dpp_f<0x121, true>(0.f, s1);
    s2 += dpp_f<0x121, true>(0.f, s2);
    sd += dpp_f<0x121, true>(0.f, sd);
    sa += dpp_f<0x121, true>(0.f, sa);

    // Lane 15 holds lengths[..., -1] (= l1.w) locally and has the full sums.
    if (sl == 15) {
        const float bg = 1.0f - sa;
        float4 o;
        o.x = s0 + bg;
        o.y = s1 + bg;
        o.z = s2 + bg;
        o.w = sd + bg * l1.w;
        ((float4*)out)[ray] = o;
    }
}

extern "C" void kernel_launch(void* const* d_in, const int* in_sizes, int n_in,
                              void* d_out, int out_size, void* d_ws, size_t ws_size,
                              hipStream_t stream) {
    const float* dens = (const float*)d_in[0];  // rays_densities (B,R,N,1)
    const float* feat = (const float*)d_in[1];  // rays_features  (B,R,N,3)
    const float* len  = (const float*)d_in[2];  // lengths        (B,R,N)
    float* out = (float*)d_out;                 // (B,R,4)

    const int n_rays = in_sizes[0] / 128;       // B*R = 131072
    const long long waves = (n_rays + 3) / 4;   // 4 rays per wave
    const long long threads = waves * 64;
    const int block = 256;
    const int grid = (int)((threads + block - 1) / block);
    raymarch_kernel<<<grid, block, 0, stream>>>(dens, feat, len, out, n_rays);
}